// Round 2
// baseline (741.586 us; speedup 1.0000x reference)
//
#include <hip/hip_runtime.h>

#define NBINS 15
#define NCLS  100
#define NSEG  (NBINS * NCLS)   // 1500
#define MAXBLK 2048
#define NGRP  64               // second-stage reduction groups
#define UNROLL 8               // float4 loads in flight per thread

// Kernel 1: stream probas with 8 float4 loads in flight per thread,
// accumulate per-block histograms in LDS, write per-block partials.
__global__ __launch_bounds__(256) void calib_accum(
    const float* __restrict__ probas,
    const int*   __restrict__ labels,
    float*       __restrict__ partA,   // [nblk][3*NSEG]
    int total4)
{
    __shared__ float s_hist[3 * NSEG];
    for (int i = threadIdx.x; i < 3 * NSEG; i += 256) s_hist[i] = 0.f;
    __syncthreads();
    float* s_cnt = s_hist;
    float* s_sum = s_hist + NSEG;
    float* s_acc = s_hist + 2 * NSEG;

    const float4* __restrict__ p4 = (const float4*)probas;
    const float inv15 = 1.0f / 15.0f;
    const int tile = 256 * UNROLL;
    const int tid = threadIdx.x;

    for (int base = blockIdx.x * tile; base < total4; base += gridDim.x * tile) {
        float4 v[UNROLL];
        int    lbl[UNROLL];
        // issue all 8 probas loads back-to-back (coalesced: lane i -> addr i)
        #pragma unroll
        for (int u = 0; u < UNROLL; ++u) {
            int i = base + u * 256 + tid;
            if (i < total4) v[u] = p4[i];
        }
        // then the label loads (L1/L2-hit heavy, 2-3 lanes share a value)
        #pragma unroll
        for (int u = 0; u < UNROLL; ++u) {
            int i = base + u * 256 + tid;
            if (i < total4) lbl[u] = labels[i / 25];
        }
        #pragma unroll
        for (int u = 0; u < UNROLL; ++u) {
            int i = base + u * 256 + tid;
            if (i >= total4) continue;
            int row = i / 25;
            int col = (i - row * 25) * 4;   // flat col of v[u].x; never crosses a row
            float pv[4] = {v[u].x, v[u].y, v[u].z, v[u].w};
            #pragma unroll
            for (int j = 0; j < 4; ++j) {
                float p = pv[j];
                int c = col + j;
                // searchsorted(bins, p, 'right') - 1: largest k with bins[k] <= p
                int k = (int)(p * 15.0f);
                if (k < NBINS && (float)(k + 1) * inv15 <= p)      ++k;
                else if (k > 0 && (float)k * inv15 > p)            --k;
                float left = (float)k * inv15;
                if (p > 0.01f && k < NBINS && p > left) {
                    int seg = c * NBINS + k;
                    atomicAdd(&s_cnt[seg], 1.0f);
                    atomicAdd(&s_sum[seg], p);
                    if (lbl[u] == c) atomicAdd(&s_acc[seg], 1.0f);
                }
            }
        }
    }
    __syncthreads();

    float* dst = partA + (size_t)blockIdx.x * (3 * NSEG);
    for (int s = threadIdx.x; s < 3 * NSEG; s += 256) dst[s] = s_hist[s];
}

// Kernel 2: NGRP-way parallel partial reduction over blocks (coalesced on s).
__global__ __launch_bounds__(256) void calib_mid(
    const float* __restrict__ partA, int nblk, int chunk,
    float*       __restrict__ partB)   // [NGRP][3*NSEG]
{
    int t = blockIdx.x * 256 + threadIdx.x;
    if (t >= NGRP * NSEG) return;
    int g = t / NSEG;
    int s = t - g * NSEG;
    int b0 = g * chunk;
    int b1 = b0 + chunk; if (b1 > nblk) b1 = nblk;
    float cnt = 0.f, sum = 0.f, acc = 0.f;
    for (int b = b0; b < b1; ++b) {
        const float* src = partA + (size_t)b * (3 * NSEG);
        cnt += src[s];
        sum += src[NSEG + s];
        acc += src[2 * NSEG + s];
    }
    float* dst = partB + (size_t)g * (3 * NSEG);
    dst[s]            = cnt;
    dst[NSEG + s]     = sum;
    dst[2 * NSEG + s] = acc;
}

// Kernel 3: final sum over NGRP groups, divide, NaN for empty bins.
__global__ __launch_bounds__(256) void calib_fin(
    const float* __restrict__ partB,
    float*       __restrict__ out)     // [confs(1500), accs(1500), n_samples(1500)]
{
    int s = blockIdx.x * 256 + threadIdx.x;
    if (s >= NSEG) return;
    float cnt = 0.f, sum = 0.f, acc = 0.f;
    #pragma unroll
    for (int g = 0; g < NGRP; ++g) {
        const float* src = partB + g * (3 * NSEG);
        cnt += src[s];
        sum += src[NSEG + s];
        acc += src[2 * NSEG + s];
    }
    float conf, accv;
    if (cnt > 0.f) { conf = sum / cnt; accv = acc / cnt; }
    else { conf = __int_as_float(0x7fc00000); accv = conf; }
    out[s]            = conf;
    out[NSEG + s]     = accv;
    out[2 * NSEG + s] = cnt;
}

extern "C" void kernel_launch(void* const* d_in, const int* in_sizes, int n_in,
                              void* d_out, int out_size, void* d_ws, size_t ws_size,
                              hipStream_t stream) {
    const float* probas = (const float*)d_in[0];
    const int*   labels = (const int*)d_in[1];
    float* out = (float*)d_out;
    float* ws  = (float*)d_ws;

    int total  = in_sizes[0];      // N*C = 50,000,000 (divisible by 4)
    int total4 = total / 4;

    // workspace: partA [nblk][3*NSEG] followed by partB [NGRP][3*NSEG]
    size_t ws_floats = ws_size / sizeof(float);
    long long avail = (long long)ws_floats - (long long)NGRP * 3 * NSEG;
    int nblk = (int)(avail / (3 * NSEG));
    if (nblk > MAXBLK) nblk = MAXBLK;
    if (nblk < 1) nblk = 1;

    float* partA = ws;
    float* partB = ws + (size_t)nblk * (3 * NSEG);

    calib_accum<<<nblk, 256, 0, stream>>>(probas, labels, partA, total4);
    int chunk = (nblk + NGRP - 1) / NGRP;
    calib_mid<<<(NGRP * NSEG + 255) / 256, 256, 0, stream>>>(partA, nblk, chunk, partB);
    calib_fin<<<(NSEG + 255) / 256, 256, 0, stream>>>(partB, out);
}

// Round 3
// 527.975 us; speedup vs baseline: 1.4046x; 1.4046x over previous
//
#include <hip/hip_runtime.h>

#define NBINS 15
#define NCLS  100
#define NSEG  (NBINS * NCLS)   // 1500
#define NGRP  64               // second-stage reduction groups
#define MAXBLK 2000            // multiple of 25 so each thread keeps its column quad
#define CHUNK 48               // iterations between register flushes (packing bound)
#define PACK  128.0f           // packed value = 128*count + sum_p  (sum_p < 48 << 128)

// bin edge b/15 correctly rounded to f32 (folded at compile time)
#define EDGE(b) ((float)((b) * (1.0 / 15.0)))

// Kernel 1: stream probas; per-thread REGISTER histograms (no LDS atomics in
// the hot loop). Thread t always sees columns [4*(t%25) .. 4*(t%25)+3] because
// the grid stride is a multiple of 25 float4s (= one row). Cumulative
// formulation: cum[b] accumulates (128+p) for every p > edge_b (and p > 0.01);
// per-bin value = cum[b] - cum[b+1]; count decoded exactly from the 128s.
__global__ __launch_bounds__(256, 4) void calib_accum(
    const float* __restrict__ probas,
    const int*   __restrict__ labels,
    float*       __restrict__ partA,   // [nblk][3*NSEG]
    int total4, int stride4)
{
    __shared__ float s_hist[3 * NSEG];
    for (int i = threadIdx.x; i < 3 * NSEG; i += 256) s_hist[i] = 0.f;
    __syncthreads();

    const float4* __restrict__ p4 = (const float4*)probas;
    const int tid0  = blockIdx.x * 256 + threadIdx.x;
    const int cquad = tid0 % 25;          // column quad: cols 4*cquad .. 4*cquad+3

    float cum[4][NBINS];
    #pragma unroll
    for (int j = 0; j < 4; ++j)
        #pragma unroll
        for (int b = 0; b < NBINS; ++b) cum[j][b] = 0.f;

    int i = tid0;
    while (i < total4) {
        #pragma unroll 2
        for (int t = 0; t < CHUNK && i < total4; ++t, i += stride4) {
            float4 v = p4[i];
            int row = i / 25;
            int lbl = labels[row];
            // rare path: this thread's quad holds the labeled column of `row`
            if ((lbl >> 2) == cquad) {
                int jj = lbl & 3;
                float p = (jj == 0) ? v.x : (jj == 1) ? v.y : (jj == 2) ? v.z : v.w;
                if (p > 0.01f) {
                    int s = 0;
                    #pragma unroll
                    for (int b = 1; b < NBINS; ++b) s += (p > EDGE(b)) ? 1 : 0;
                    atomicAdd(&s_hist[2 * NSEG + lbl * NBINS + s], 1.0f);
                }
            }
            float pv[4] = {v.x, v.y, v.z, v.w};
            #pragma unroll
            for (int j = 0; j < 4; ++j) {
                float add = PACK + pv[j];
                #pragma unroll
                for (int b = 0; b < NBINS; ++b) {
                    float edge = (b == 0) ? 0.01f : EDGE(b);
                    cum[j][b] += (pv[j] > edge) ? add : 0.f;
                }
            }
        }
        // flush registers -> block LDS histogram (exact count decode)
        #pragma unroll
        for (int j = 0; j < 4; ++j) {
            int col = 4 * cquad + j;
            #pragma unroll
            for (int b = 0; b < NBINS; ++b) {
                float binv = cum[j][b] - ((b < NBINS - 1) ? cum[j][b + 1] : 0.f);
                cum[j][b] = 0.f;
                if (binv > 0.f) {
                    float cntf = floorf(binv * (1.0f / PACK) + 0.5f);
                    float sump = binv - PACK * cntf;
                    int seg = col * NBINS + b;
                    atomicAdd(&s_hist[seg], cntf);
                    atomicAdd(&s_hist[NSEG + seg], sump);
                }
            }
        }
    }
    __syncthreads();

    float* dst = partA + (size_t)blockIdx.x * (3 * NSEG);
    for (int s = threadIdx.x; s < 3 * NSEG; s += 256) dst[s] = s_hist[s];
}

// Kernel 2: NGRP-way parallel partial reduction over blocks (coalesced on s).
__global__ __launch_bounds__(256) void calib_mid(
    const float* __restrict__ partA, int nblk, int chunk,
    float*       __restrict__ partB)   // [NGRP][3*NSEG]
{
    int t = blockIdx.x * 256 + threadIdx.x;
    if (t >= NGRP * NSEG) return;
    int g = t / NSEG;
    int s = t - g * NSEG;
    int b0 = g * chunk;
    int b1 = b0 + chunk; if (b1 > nblk) b1 = nblk;
    float cnt = 0.f, sum = 0.f, acc = 0.f;
    for (int b = b0; b < b1; ++b) {
        const float* src = partA + (size_t)b * (3 * NSEG);
        cnt += src[s];
        sum += src[NSEG + s];
        acc += src[2 * NSEG + s];
    }
    float* dst = partB + (size_t)g * (3 * NSEG);
    dst[s]            = cnt;
    dst[NSEG + s]     = sum;
    dst[2 * NSEG + s] = acc;
}

// Kernel 3: final sum over NGRP groups, divide, NaN for empty bins.
__global__ __launch_bounds__(256) void calib_fin(
    const float* __restrict__ partB,
    float*       __restrict__ out)     // [confs(1500), accs(1500), n_samples(1500)]
{
    int s = blockIdx.x * 256 + threadIdx.x;
    if (s >= NSEG) return;
    float cnt = 0.f, sum = 0.f, acc = 0.f;
    #pragma unroll
    for (int g = 0; g < NGRP; ++g) {
        const float* src = partB + g * (3 * NSEG);
        cnt += src[s];
        sum += src[NSEG + s];
        acc += src[2 * NSEG + s];
    }
    float conf, accv;
    if (cnt > 0.f) { conf = sum / cnt; accv = acc / cnt; }
    else { conf = __int_as_float(0x7fc00000); accv = conf; }
    out[s]            = conf;
    out[NSEG + s]     = accv;
    out[2 * NSEG + s] = cnt;
}

extern "C" void kernel_launch(void* const* d_in, const int* in_sizes, int n_in,
                              void* d_out, int out_size, void* d_ws, size_t ws_size,
                              hipStream_t stream) {
    const float* probas = (const float*)d_in[0];
    const int*   labels = (const int*)d_in[1];
    float* out = (float*)d_out;
    float* ws  = (float*)d_ws;

    int total  = in_sizes[0];      // N*C = 50,000,000 (divisible by 4; 100 cols)
    int total4 = total / 4;

    // workspace: partA [nblk][3*NSEG] followed by partB [NGRP][3*NSEG]
    size_t ws_floats = ws_size / sizeof(float);
    long long avail = (long long)ws_floats - (long long)NGRP * 3 * NSEG;
    int nblk = (int)(avail / (3 * NSEG));
    if (nblk > MAXBLK) nblk = MAXBLK;
    nblk = (nblk / 25) * 25;       // grid stride must be a multiple of one row
    if (nblk < 25) nblk = 25;

    float* partA = ws;
    float* partB = ws + (size_t)nblk * (3 * NSEG);

    calib_accum<<<nblk, 256, 0, stream>>>(probas, labels, partA, total4, nblk * 256);
    int chunk = (nblk + NGRP - 1) / NGRP;
    calib_mid<<<(NGRP * NSEG + 255) / 256, 256, 0, stream>>>(partA, nblk, chunk, partB);
    calib_fin<<<(NSEG + 255) / 256, 256, 0, stream>>>(partB, out);
}

// Round 4
// 487.989 us; speedup vs baseline: 1.5197x; 1.0819x over previous
//
#include <hip/hip_runtime.h>

#define NBINS 15
#define NCLS  100
#define NSEG  (NBINS * NCLS)   // 1500
#define NGRP  64               // second-stage reduction groups
#define NBLK  512              // 2 blocks/CU
#define TR    96               // tile rows
#define BLK   320              // 5 waves; 300 compute threads = 3 per column

// bin edge b/15 correctly rounded to f32 (folded at compile time)
#define EDGE(b) ((float)((b) * (1.0 / 15.0)))

// Kernel 1: tile probas into LDS (coalesced float4), each thread owns ONE
// column with a 15-bin register histogram (int counts = exact, float sums).
// Cumulative edge-compare is branchless; flush once at kernel end.
__global__ __launch_bounds__(BLK, 2) void calib_accum(
    const float* __restrict__ probas,
    const int*   __restrict__ labels,
    float*       __restrict__ partA,   // [nblk][3*NSEG]
    int N, int rowsPerBlk)
{
    __shared__ float tile[TR * NCLS];      // 38.4 KB
    __shared__ float s_hist[3 * NSEG];     // 18.0 KB
    const int t = threadIdx.x;
    for (int i = t; i < 3 * NSEG; i += BLK) s_hist[i] = 0.f;

    const int r0 = blockIdx.x * rowsPerBlk;
    int r1 = r0 + rowsPerBlk; if (r1 > N) r1 = N;

    const int col  = t % NCLS;       // valid for t < 300
    const int sub  = t / NCLS;       // 0,1,2
    const int rbase = sub * 32;      // rows rbase..rbase+31 of the tile

    int   cc[NBINS];
    float cs[NBINS];
    #pragma unroll
    for (int b = 0; b < NBINS; ++b) { cc[b] = 0; cs[b] = 0.f; }

    const float4* __restrict__ p4 = (const float4*)probas;

    for (int rb = r0; rb < r1; rb += TR) {
        __syncthreads();                       // tile reuse + s_hist init safety
        const int nrow = (r1 - rb < TR) ? (r1 - rb) : TR;
        // stage tile: TR*25 float4s, coalesced; zero rows beyond this block's band
        for (int i = t; i < TR * 25; i += BLK) {
            int rr = i / 25;
            float4 v;
            if (rr < nrow) v = p4[(size_t)rb * 25 + i];
            else { v.x = 0.f; v.y = 0.f; v.z = 0.f; v.w = 0.f; }
            *(float4*)&tile[i * 4] = v;
        }
        __syncthreads();

        // label path: one lane per row of the tile
        if (t < nrow) {
            int lbl = labels[rb + t];
            float p = tile[t * NCLS + lbl];
            if (p > 0.01f) {
                int s = 0;
                #pragma unroll
                for (int b = 1; b < NBINS; ++b) s += (p > EDGE(b)) ? 1 : 0;
                atomicAdd(&s_hist[2 * NSEG + lbl * NBINS + s], 1.0f);
            }
        }

        // hot path: walk own column; zero-filled rows auto-fail p > 0.01
        if (t < 300) {
            const float* tcol = &tile[col];
            #pragma unroll 8
            for (int r = 0; r < 32; ++r) {
                float p = tcol[(rbase + r) * NCLS];
                #pragma unroll
                for (int b = 0; b < NBINS; ++b) {
                    float e = (b == 0) ? 0.01f : EDGE(b);
                    bool g = p > e;
                    cc[b] += g ? 1 : 0;
                    cs[b] += g ? p : 0.f;
                }
            }
        }
    }

    // flush: cumulative -> per-bin via adjacent difference (counts exact)
    if (t < 300) {
        #pragma unroll
        for (int b = 0; b < NBINS; ++b) {
            int   c  = cc[b] - ((b < NBINS - 1) ? cc[b + 1] : 0);
            float sp = cs[b] - ((b < NBINS - 1) ? cs[b + 1] : 0.f);
            int seg = col * NBINS + b;
            atomicAdd(&s_hist[seg], (float)c);
            atomicAdd(&s_hist[NSEG + seg], sp);
        }
    }
    __syncthreads();

    float* dst = partA + (size_t)blockIdx.x * (3 * NSEG);
    for (int s = t; s < 3 * NSEG; s += BLK) dst[s] = s_hist[s];
}

// Kernel 2: NGRP-way parallel partial reduction over blocks (coalesced on s).
__global__ __launch_bounds__(256) void calib_mid(
    const float* __restrict__ partA, int nblk, int chunk,
    float*       __restrict__ partB)   // [NGRP][3*NSEG]
{
    int t = blockIdx.x * 256 + threadIdx.x;
    if (t >= NGRP * NSEG) return;
    int g = t / NSEG;
    int s = t - g * NSEG;
    int b0 = g * chunk;
    int b1 = b0 + chunk; if (b1 > nblk) b1 = nblk;
    float cnt = 0.f, sum = 0.f, acc = 0.f;
    for (int b = b0; b < b1; ++b) {
        const float* src = partA + (size_t)b * (3 * NSEG);
        cnt += src[s];
        sum += src[NSEG + s];
        acc += src[2 * NSEG + s];
    }
    float* dst = partB + (size_t)g * (3 * NSEG);
    dst[s]            = cnt;
    dst[NSEG + s]     = sum;
    dst[2 * NSEG + s] = acc;
}

// Kernel 3: final sum over NGRP groups, divide, NaN for empty bins.
__global__ __launch_bounds__(256) void calib_fin(
    const float* __restrict__ partB,
    float*       __restrict__ out)     // [confs(1500), accs(1500), n_samples(1500)]
{
    int s = blockIdx.x * 256 + threadIdx.x;
    if (s >= NSEG) return;
    float cnt = 0.f, sum = 0.f, acc = 0.f;
    #pragma unroll
    for (int g = 0; g < NGRP; ++g) {
        const float* src = partB + g * (3 * NSEG);
        cnt += src[s];
        sum += src[NSEG + s];
        acc += src[2 * NSEG + s];
    }
    float conf, accv;
    if (cnt > 0.f) { conf = sum / cnt; accv = acc / cnt; }
    else { conf = __int_as_float(0x7fc00000); accv = conf; }
    out[s]            = conf;
    out[NSEG + s]     = accv;
    out[2 * NSEG + s] = cnt;
}

extern "C" void kernel_launch(void* const* d_in, const int* in_sizes, int n_in,
                              void* d_out, int out_size, void* d_ws, size_t ws_size,
                              hipStream_t stream) {
    const float* probas = (const float*)d_in[0];
    const int*   labels = (const int*)d_in[1];
    float* out = (float*)d_out;
    float* ws  = (float*)d_ws;

    int N = in_sizes[1];           // rows (labels count), 500000; C fixed at 100

    // workspace: partA [nblk][3*NSEG] followed by partB [NGRP][3*NSEG]
    size_t ws_floats = ws_size / sizeof(float);
    long long avail = (long long)ws_floats - (long long)NGRP * 3 * NSEG;
    int nblk = (int)(avail / (3 * NSEG));
    if (nblk > NBLK) nblk = NBLK;
    if (nblk < 1) nblk = 1;

    float* partA = ws;
    float* partB = ws + (size_t)nblk * (3 * NSEG);

    int rowsPerBlk = (N + nblk - 1) / nblk;

    calib_accum<<<nblk, BLK, 0, stream>>>(probas, labels, partA, N, rowsPerBlk);
    int chunk = (nblk + NGRP - 1) / NGRP;
    calib_mid<<<(NGRP * NSEG + 255) / 256, 256, 0, stream>>>(partA, nblk, chunk, partB);
    calib_fin<<<(NSEG + 255) / 256, 256, 0, stream>>>(partB, out);
}

// Round 5
// 367.121 us; speedup vs baseline: 2.0200x; 1.3292x over previous
//
#include <hip/hip_runtime.h>

#define NBINS 15
#define NCLS  100
#define NSEG  (NBINS * NCLS)   // 1500
#define NGRP  64               // second-stage reduction groups
#define NBLK  768              // 3 blocks/CU dispatched; 4 fit by LDS
#define TR    48               // tile rows (LDS tile = 19.2 KB)
#define BLK   256
#define HOT   200              // threads 0..199: (col, half) ownership, 24 rows each

#define INV15 (1.0f / 15.0f)
#define EDGE(b) ((float)(b) * INV15)   // matches reference/np edge arithmetic (round-2 proven)

// Kernel 1: tile probas into LDS (coalesced float4), each hot thread owns ONE
// column half (24 rows) with a 15-bin register histogram (int counts = exact).
// Fully-unrolled column walk -> ds_read_b32 with immediate offsets, no per-read
// address math. Flush once at kernel end.
__global__ __launch_bounds__(BLK) void calib_accum(
    const float* __restrict__ probas,
    const int*   __restrict__ labels,
    float*       __restrict__ partA,   // [nblk][3*NSEG]
    int N, int rowsPerBlk)
{
    __shared__ float tile[TR * NCLS];      // 19.2 KB
    __shared__ float s_hist[3 * NSEG];     // 18.0 KB
    const int t = threadIdx.x;
    for (int i = t; i < 3 * NSEG; i += BLK) s_hist[i] = 0.f;

    const int r0 = blockIdx.x * rowsPerBlk;
    int r1 = r0 + rowsPerBlk; if (r1 > N) r1 = N;

    const int col   = t % NCLS;        // valid for t < HOT
    const int rbase = (t / NCLS) * 24; // 0 or 24

    int   cc[NBINS];
    float cs[NBINS];
    #pragma unroll
    for (int b = 0; b < NBINS; ++b) { cc[b] = 0; cs[b] = 0.f; }

    const float4* __restrict__ p4 = (const float4*)probas;

    for (int rb = r0; rb < r1; rb += TR) {
        __syncthreads();                       // tile reuse barrier
        const int nrow = (r1 - rb < TR) ? (r1 - rb) : TR;
        // stage tile: TR*25 float4s, coalesced; zero-fill rows past the band
        for (int i = t; i < TR * 25; i += BLK) {
            float4 v;
            if (i < nrow * 25) v = p4[(size_t)rb * 25 + i];
            else { v.x = 0.f; v.y = 0.f; v.z = 0.f; v.w = 0.f; }
            *(float4*)&tile[i * 4] = v;
        }
        __syncthreads();

        // label path: one lane per row; round-2-proven direct-k logic
        if (t < nrow) {
            int lbl = labels[rb + t];
            float p = tile[t * NCLS + lbl];
            int k = (int)(p * 15.0f);
            if (k < NBINS && (float)(k + 1) * INV15 <= p)      ++k;
            else if (k > 0 && (float)k * INV15 > p)            --k;
            if (p > 0.01f && k < NBINS && p > (float)k * INV15) {
                atomicAdd(&s_hist[2 * NSEG + lbl * NBINS + k], 1.0f);
            }
        }

        // hot path: walk own column half; zero rows auto-fail p > 0.01
        if (t < HOT) {
            const float* tcol = &tile[rbase * NCLS + col];
            #pragma unroll
            for (int r = 0; r < 24; ++r) {
                float p = tcol[r * NCLS];      // imm-offset ds_read_b32
                #pragma unroll
                for (int b = 0; b < NBINS; ++b) {
                    float e = (b == 0) ? 0.01f : EDGE(b);
                    bool g = p > e;
                    cc[b] += g ? 1 : 0;
                    cs[b] += g ? p : 0.f;
                }
            }
        }
    }

    // flush: cumulative -> per-bin via adjacent difference (counts exact ints)
    if (t < HOT) {
        #pragma unroll
        for (int b = 0; b < NBINS; ++b) {
            int   c  = cc[b] - ((b < NBINS - 1) ? cc[b + 1] : 0);
            float sp = cs[b] - ((b < NBINS - 1) ? cs[b + 1] : 0.f);
            int seg = col * NBINS + b;
            atomicAdd(&s_hist[seg], (float)c);
            atomicAdd(&s_hist[NSEG + seg], sp);
        }
    }
    __syncthreads();

    float* dst = partA + (size_t)blockIdx.x * (3 * NSEG);
    for (int s = t; s < 3 * NSEG; s += BLK) dst[s] = s_hist[s];
}

// Kernel 2: NGRP-way parallel partial reduction over blocks (coalesced on s).
__global__ __launch_bounds__(256) void calib_mid(
    const float* __restrict__ partA, int nblk, int chunk,
    float*       __restrict__ partB)   // [NGRP][3*NSEG]
{
    int t = blockIdx.x * 256 + threadIdx.x;
    if (t >= NGRP * NSEG) return;
    int g = t / NSEG;
    int s = t - g * NSEG;
    int b0 = g * chunk;
    int b1 = b0 + chunk; if (b1 > nblk) b1 = nblk;
    float cnt = 0.f, sum = 0.f, acc = 0.f;
    for (int b = b0; b < b1; ++b) {
        const float* src = partA + (size_t)b * (3 * NSEG);
        cnt += src[s];
        sum += src[NSEG + s];
        acc += src[2 * NSEG + s];
    }
    float* dst = partB + (size_t)g * (3 * NSEG);
    dst[s]            = cnt;
    dst[NSEG + s]     = sum;
    dst[2 * NSEG + s] = acc;
}

// Kernel 3: final sum over NGRP groups, divide, NaN for empty bins.
__global__ __launch_bounds__(256) void calib_fin(
    const float* __restrict__ partB,
    float*       __restrict__ out)     // [confs(1500), accs(1500), n_samples(1500)]
{
    int s = blockIdx.x * 256 + threadIdx.x;
    if (s >= NSEG) return;
    float cnt = 0.f, sum = 0.f, acc = 0.f;
    #pragma unroll
    for (int g = 0; g < NGRP; ++g) {
        const float* src = partB + g * (3 * NSEG);
        cnt += src[s];
        sum += src[NSEG + s];
        acc += src[2 * NSEG + s];
    }
    float conf, accv;
    if (cnt > 0.f) { conf = sum / cnt; accv = acc / cnt; }
    else { conf = __int_as_float(0x7fc00000); accv = conf; }
    out[s]            = conf;
    out[NSEG + s]     = accv;
    out[2 * NSEG + s] = cnt;
}

extern "C" void kernel_launch(void* const* d_in, const int* in_sizes, int n_in,
                              void* d_out, int out_size, void* d_ws, size_t ws_size,
                              hipStream_t stream) {
    const float* probas = (const float*)d_in[0];
    const int*   labels = (const int*)d_in[1];
    float* out = (float*)d_out;
    float* ws  = (float*)d_ws;

    int N = in_sizes[1];           // rows (labels count); C fixed at 100

    // workspace: partA [nblk][3*NSEG] followed by partB [NGRP][3*NSEG]
    size_t ws_floats = ws_size / sizeof(float);
    long long avail = (long long)ws_floats - (long long)NGRP * 3 * NSEG;
    int nblk = (int)(avail / (3 * NSEG));
    if (nblk > NBLK) nblk = NBLK;
    if (nblk < 1) nblk = 1;

    float* partA = ws;
    float* partB = ws + (size_t)nblk * (3 * NSEG);

    int rowsPerBlk = (N + nblk - 1) / nblk;

    calib_accum<<<nblk, BLK, 0, stream>>>(probas, labels, partA, N, rowsPerBlk);
    int chunk = (nblk + NGRP - 1) / NGRP;
    calib_mid<<<(NGRP * NSEG + 255) / 256, 256, 0, stream>>>(partA, nblk, chunk, partB);
    calib_fin<<<(NSEG + 255) / 256, 256, 0, stream>>>(partB, out);
}

// Round 6
// 294.616 us; speedup vs baseline: 2.5171x; 1.2461x over previous
//
#include <hip/hip_runtime.h>

#define NBINS 15
#define NCLS  100
#define NSEG  (NBINS * NCLS)   // 1500
#define NGRP  64               // second-stage reduction groups
#define MAXBLK 2048            // 8 blocks/CU
#define BLK   256
#define SUMSCALE 2048.0f       // fixed-point scale for packed sum (20-bit field)
#define INV15 (1.0f / 15.0f)   // f32 edge arithmetic (round-2/5 proven vs np)

// Kernel 1: grid-stride float4 stream; compute bin index k directly (exact
// searchsorted-right semantics) and do ONE packed LDS atomic per element:
// u32 = (1<<20) | round(p*2048). Fire-and-forget ds_add_u32 - no RMW chain,
// no O(NBINS) compare cascade. Counts exact ints; sum quantized at 2^-11
// (conf error ~1e-6). Label-match counts exact in a separate u32 region.
__global__ __launch_bounds__(BLK) void calib_accum(
    const float* __restrict__ probas,
    const int*   __restrict__ labels,
    float*       __restrict__ partA,   // [nblk][3*NSEG]
    int total4)
{
    __shared__ unsigned int s_pk[NSEG];   // packed: cnt<<20 | sum*2048
    __shared__ unsigned int s_ac[NSEG];   // label-match counts
    const int t = threadIdx.x;
    for (int i = t; i < NSEG; i += BLK) { s_pk[i] = 0u; s_ac[i] = 0u; }
    __syncthreads();

    const float4* __restrict__ p4 = (const float4*)probas;
    const int stride = gridDim.x * BLK;

    for (int i = blockIdx.x * BLK + t; i < total4; i += stride) {
        float4 v = p4[i];
        int row  = i / 25;              // compiler magic-div
        int col0 = (i - row * 25) * 4;  // float4 never crosses a row (100%4==0)
        int lbl  = labels[row];
        float pv[4] = {v.x, v.y, v.z, v.w};
        #pragma unroll
        for (int j = 0; j < 4; ++j) {
            float p = pv[j];
            int c = col0 + j;
            // searchsorted(bins, p, 'right') - 1: largest k with bins[k] <= p
            int k = (int)(p * 15.0f);
            if (k < NBINS && (float)(k + 1) * INV15 <= p)      ++k;
            else if (k > 0 && (float)k * INV15 > p)            --k;
            float left = (float)k * INV15;
            if (p > 0.01f && k < NBINS && p > left) {
                int seg = c * NBINS + k;
                unsigned int pk = (1u << 20) | (unsigned int)(p * SUMSCALE + 0.5f);
                atomicAdd(&s_pk[seg], pk);
                if (lbl == c) atomicAdd(&s_ac[seg], 1u);
            }
        }
    }
    __syncthreads();

    // decode + flush per-block partials
    float* dst = partA + (size_t)blockIdx.x * (3 * NSEG);
    for (int s = t; s < NSEG; s += BLK) {
        unsigned int pk = s_pk[s];
        dst[s]            = (float)(pk >> 20);
        dst[NSEG + s]     = (float)(pk & 0xFFFFFu) * (1.0f / SUMSCALE);
        dst[2 * NSEG + s] = (float)s_ac[s];
    }
}

// Kernel 2: NGRP-way parallel partial reduction over blocks (coalesced on s).
__global__ __launch_bounds__(256) void calib_mid(
    const float* __restrict__ partA, int nblk, int chunk,
    float*       __restrict__ partB)   // [NGRP][3*NSEG]
{
    int t = blockIdx.x * 256 + threadIdx.x;
    if (t >= NGRP * NSEG) return;
    int g = t / NSEG;
    int s = t - g * NSEG;
    int b0 = g * chunk;
    int b1 = b0 + chunk; if (b1 > nblk) b1 = nblk;
    float cnt = 0.f, sum = 0.f, acc = 0.f;
    for (int b = b0; b < b1; ++b) {
        const float* src = partA + (size_t)b * (3 * NSEG);
        cnt += src[s];
        sum += src[NSEG + s];
        acc += src[2 * NSEG + s];
    }
    float* dst = partB + (size_t)g * (3 * NSEG);
    dst[s]            = cnt;
    dst[NSEG + s]     = sum;
    dst[2 * NSEG + s] = acc;
}

// Kernel 3: final sum over NGRP groups, divide, NaN for empty bins.
__global__ __launch_bounds__(256) void calib_fin(
    const float* __restrict__ partB,
    float*       __restrict__ out)     // [confs(1500), accs(1500), n_samples(1500)]
{
    int s = blockIdx.x * 256 + threadIdx.x;
    if (s >= NSEG) return;
    float cnt = 0.f, sum = 0.f, acc = 0.f;
    #pragma unroll
    for (int g = 0; g < NGRP; ++g) {
        const float* src = partB + g * (3 * NSEG);
        cnt += src[s];
        sum += src[NSEG + s];
        acc += src[2 * NSEG + s];
    }
    float conf, accv;
    if (cnt > 0.f) { conf = sum / cnt; accv = acc / cnt; }
    else { conf = __int_as_float(0x7fc00000); accv = conf; }
    out[s]            = conf;
    out[NSEG + s]     = accv;
    out[2 * NSEG + s] = cnt;
}

extern "C" void kernel_launch(void* const* d_in, const int* in_sizes, int n_in,
                              void* d_out, int out_size, void* d_ws, size_t ws_size,
                              hipStream_t stream) {
    const float* probas = (const float*)d_in[0];
    const int*   labels = (const int*)d_in[1];
    float* out = (float*)d_out;
    float* ws  = (float*)d_ws;

    int total  = in_sizes[0];      // N*C = 50,000,000 (divisible by 4; C=100)
    int total4 = total / 4;

    // workspace: partA [nblk][3*NSEG] followed by partB [NGRP][3*NSEG]
    size_t ws_floats = ws_size / sizeof(float);
    long long avail = (long long)ws_floats - (long long)NGRP * 3 * NSEG;
    int nblk = (int)(avail / (3 * NSEG));
    if (nblk > MAXBLK) nblk = MAXBLK;
    if (nblk < 1) nblk = 1;

    float* partA = ws;
    float* partB = ws + (size_t)nblk * (3 * NSEG);

    calib_accum<<<nblk, BLK, 0, stream>>>(probas, labels, partA, total4);
    int chunk = (nblk + NGRP - 1) / NGRP;
    calib_mid<<<(NGRP * NSEG + 255) / 256, 256, 0, stream>>>(partA, nblk, chunk, partB);
    calib_fin<<<(NSEG + 255) / 256, 256, 0, stream>>>(partB, out);
}